// Round 3
// baseline (338.029 us; speedup 1.0000x reference)
//
#include <hip/hip_runtime.h>
#include <hip/hip_bf16.h>

typedef __bf16 bf16x8 __attribute__((ext_vector_type(8)));
typedef float f32x4 __attribute__((ext_vector_type(4)));

#define HH 112
#define WW 112
#define CIN 128
#define COUT 128
#define HP 114          // padded H (pad=1 baked into xt)
#define WP 114

#define RRV 10          // staged rows (8 out + 2 halo)
#define RCV 18          // staged cols (16 out + 2 halo)
#define NQ (RRV * RCV * 4)   // 720 16B-quads per 32-channel chunk

// 16B-quad XOR swizzle (involution): spreads the 64B-cell-stride read
// pattern across all 8 LDS bank-groups. Applied to global SOURCE of
// global_load_lds (dest must stay linear) and to the ds_read address.
__device__ __forceinline__ int swz(int Q) { return Q ^ ((Q >> 3) & 7); }

// ---------------- weight repack: w[o][c][3][3] f32 -> wb[tap][o][c] bf16 ----
__global__ void wino_prep_weights(const float* __restrict__ w,
                                  __hip_bfloat16* __restrict__ wb) {
    int t = blockIdx.x * 256 + threadIdx.x;
    if (t >= 9 * COUT * CIN) return;
    int c = t & (CIN - 1);
    int o = (t >> 7) & (COUT - 1);
    int r = t >> 14;                       // tap 0..8
    wb[t] = __float2bfloat16(w[(o * CIN + c) * 9 + r]);
}

// ---------------- zero the pad border of xt ---------------------------------
__global__ void pad_borders(__hip_bfloat16* __restrict__ xt) {
    int q = blockIdx.x * 256 + threadIdx.x;       // 16B chunks over border cells
    int n = blockIdx.y;
    if (q >= 452 * 16) return;
    int chunk = q & 15;
    int cell = q >> 4;                            // 0..451
    int hp, wp;
    if (cell < 114)      { hp = 0;          wp = cell; }
    else if (cell < 228) { hp = 113;        wp = cell - 114; }
    else if (cell < 340) { hp = cell - 227; wp = 0; }      // 1..112
    else                 { hp = cell - 339; wp = 113; }    // 1..112
    bf16x8 z = {};
    *reinterpret_cast<bf16x8*>(xt + ((size_t)(n * HP + hp) * WP + wp) * CIN + chunk * 8) = z;
}

// ---------------- x[n][c][112][112] f32 -> xt[n][114][114][128] bf16 --------
// LDS-free transpose: thread owns a channel PAIR (c=2cp, 2cp+1) over 56 w.
// Reads: fully coalesced float4. Stores: packed b32 {c even, c odd}; one
// wave-instruction writes 256B contiguous (all 64 cp at fixed h,w).
__global__ __launch_bounds__(256) void transpose_pad(
        const float* __restrict__ x, __hip_bfloat16* __restrict__ xt) {
    const int t = threadIdx.x;
    const int cp = t & 63;          // channel pair index
    const int ws = (t >> 6) & 1;    // w half (56 each)
    const int hh = t >> 7;          // h sub-row
    const int h = blockIdx.x * 2 + hh;
    const int n = blockIdx.y;

    const float* s0 = x + (((size_t)(n * CIN + cp * 2) * HH + h) * WW) + ws * 56;
    const float* s1 = s0 + (size_t)HH * WW;
    f32x4 a[14], b[14];
#pragma unroll
    for (int k = 0; k < 14; ++k) a[k] = *reinterpret_cast<const f32x4*>(s0 + k * 4);
#pragma unroll
    for (int k = 0; k < 14; ++k) b[k] = *reinterpret_cast<const f32x4*>(s1 + k * 4);

    unsigned* dst = reinterpret_cast<unsigned*>(xt) +
                    ((size_t)(n * HP + h + 1) * WP + (ws * 56 + 1)) * (CIN / 2) + cp;
#pragma unroll
    for (int k = 0; k < 56; ++k) {
        union { __hip_bfloat16 e[2]; unsigned u; } p;
        p.e[0] = __float2bfloat16(a[k >> 2][k & 3]);
        p.e[1] = __float2bfloat16(b[k >> 2][k & 3]);
        dst[(size_t)k * (CIN / 2)] = p.u;
    }
}

__device__ __forceinline__ void gload_lds16(const __hip_bfloat16* g, __hip_bfloat16* l) {
    __builtin_amdgcn_global_load_lds(
        (const __attribute__((address_space(1))) unsigned int*)g,
        (__attribute__((address_space(3))) unsigned int*)l, 16, 0, 0);
}

// ---------------- conv: implicit GEMM, 128 O x (16x8) px per block ----------
// 4 waves: wo = wv>>1 (64-O half), wp = wv&1 (4-row half). grid (7,14,16).
// Loop order (dx -> row -> dy): each LDS fragment feeds up to 12 MFMAs.
// Operand order mfma(x, w): D reg-dim = w-pixel -> float4 epilogue stores.
__global__ __launch_bounds__(256, 3) void conv3x3_mfma(
        const __hip_bfloat16* __restrict__ xt, const __hip_bfloat16* __restrict__ wb,
        const float* __restrict__ bias, float* __restrict__ out) {
    __shared__ __align__(16) __hip_bfloat16 xs[2][NQ * 8];

    const int ox0 = blockIdx.x * 16, oy0 = blockIdx.y * 8;
    const int n = blockIdx.z;
    const int tid = threadIdx.x;
    const int lane = tid & 63;
    const int wv = tid >> 6;
    const int wo = wv >> 1;
    const int wp = wv & 1;
    const int l15 = lane & 15;
    const int lg = lane >> 4;

    f32x4 acc[4][4];
#pragma unroll
    for (int i = 0; i < 4; ++i)
#pragma unroll
        for (int j = 0; j < 4; ++j) acc[i][j] = (f32x4){0.f, 0.f, 0.f, 0.f};

    const __hip_bfloat16* gb0 = xt + (((size_t)n * HP + oy0) * WP + ox0) * CIN;

    // staging map: LDS slot q (linear, forced by global_load_lds) receives
    // global quad Q = swz(q)  (swz is an involution)
    int g_off[3];
#pragma unroll
    for (int it = 0; it < 3; ++it) {
        int q = tid + it * 256;
        if (q < NQ) {
            int Q = swz(q);
            int cell = Q >> 2;
            int row = cell / RCV;
            int col = cell - row * RCV;
            g_off[it] = (row * WP + col) * CIN + (Q & 3) * 8;
        } else {
            g_off[it] = 0;
        }
    }

    auto stage = [&](int buf, int cc) {
#pragma unroll
        for (int it = 0; it < 3; ++it) {
            int q = tid + it * 256;
            if (q < NQ)
                gload_lds16(gb0 + cc * 32 + g_off[it], &xs[buf][q * 8]);
        }
    };

    const int qbase = ((wp * 4) * RCV + l15) * 4 + lg;

    stage(0, 0);
    __syncthreads();

#pragma unroll 1
    for (int cc = 0; cc < 4; ++cc) {
        if (cc < 3) stage((cc + 1) & 1, cc + 1);
        const __hip_bfloat16* xb = xs[cc & 1];
        const int cb = cc * 32;
#pragma unroll
        for (int dx = 0; dx < 3; ++dx) {
            // hoist the 12 weight frags for this dx (L2-resident)
            bf16x8 Wf[3][4];
#pragma unroll
            for (int dy = 0; dy < 3; ++dy)
#pragma unroll
                for (int os = 0; os < 4; ++os)
                    Wf[dy][os] = *reinterpret_cast<const bf16x8*>(
                        wb + ((size_t)((dy * 3 + dx) * COUT) + wo * 64 + os * 16 + l15) * CIN
                           + cb + lg * 8);
#pragma unroll
            for (int r = 0; r < 6; ++r) {
                int Q = qbase + r * (RCV * 4) + dx * 4;
                bf16x8 F = *reinterpret_cast<const bf16x8*>(&xb[swz(Q) * 8]);
#pragma unroll
                for (int dy = 0; dy < 3; ++dy) {
                    int ps = r - dy;
                    if (ps >= 0 && ps < 4) {
#pragma unroll
                        for (int os = 0; os < 4; ++os)
                            acc[os][ps] = __builtin_amdgcn_mfma_f32_16x16x32_bf16(
                                F, Wf[dy][os], acc[os][ps], 0, 0, 0);
                    }
                }
            }
        }
        __syncthreads();   // buffer handoff + drains this cc's prefetch
    }

    // epilogue: D col(l15) = o, D reg-dim = w-pixel -> float4 stores
#pragma unroll
    for (int os = 0; os < 4; ++os) {
        int o = wo * 64 + os * 16 + l15;
        float bv = bias[o];
#pragma unroll
        for (int ps = 0; ps < 4; ++ps) {
            f32x4 v;
#pragma unroll
            for (int e = 0; e < 4; ++e) v[e] = acc[os][ps][e] + bv;
            *reinterpret_cast<f32x4*>(
                out + (((size_t)(n * COUT + o) * HH + oy0 + wp * 4 + ps) * WW) + ox0 + lg * 4) = v;
        }
    }
}

extern "C" void kernel_launch(void* const* d_in, const int* in_sizes, int n_in,
                              void* d_out, int out_size, void* d_ws, size_t ws_size,
                              hipStream_t stream) {
    const float* x = (const float*)d_in[0];
    const float* w = (const float*)d_in[1];
    const float* bias = (const float*)d_in[2];
    float* out = (float*)d_out;

    __hip_bfloat16* xt = (__hip_bfloat16*)d_ws;                       // 16*114*114*128*2 = 53,231,616 B
    __hip_bfloat16* wb = (__hip_bfloat16*)((char*)d_ws + 53231616);   // 294,912 B

    hipLaunchKernelGGL(wino_prep_weights, dim3(576), dim3(256), 0, stream, w, wb);
    hipLaunchKernelGGL(pad_borders, dim3((452 * 16 + 255) / 256, 16), dim3(256), 0, stream, xt);
    hipLaunchKernelGGL(transpose_pad, dim3(56, 16), dim3(256), 0, stream, x, xt);
    hipLaunchKernelGGL(conv3x3_mfma, dim3(7, 14, 16), dim3(256), 0, stream,
                       xt, wb, bias, out);
}